// Round 1
// baseline (593.226 us; speedup 1.0000x reference)
//
#include <hip/hip_runtime.h>

// CompositionalEmbedding on MI355X.
// Algebraic restructure:
//   qkv[n,t,:] = mask[n,t] * (in_proj_w @ comp_t) + in_proj_b, comp_t from one of
//   140 distinct table rows (or values[n]*val_w + val_b)  -> precompute projected tables.
//   mean over query tokens commutes with attn@V:  mean_o = sum_k w[k]*V[k],
//   w[k] = (1/5) sum_q attn[q,k].
//   out = mean_o @ (out_w@out_proj_w)^T + (out_w@out_proj_b + out_b)  -> fused W2/b2.
// Final GEMM [N,128]@[128,768] via bf16 MFMA 16x16x32 (fp32 accumulate).

typedef __attribute__((ext_vector_type(8))) short bf16x8;   // 8 bf16 = 4 VGPRs
typedef __attribute__((ext_vector_type(4))) float floatx4;  // MFMA accumulator

__device__ __forceinline__ unsigned short f32_bf16(float f) {
  unsigned int x = __float_as_uint(f);
  x += 0x7FFFu + ((x >> 16) & 1u);   // RNE
  return (unsigned short)(x >> 16);
}

// ---------------- P1: proj_all[142][384] = in_proj_w @ {table rows, val_w, val_b}
// rows 0-9 dev, 10-19 pseudo, 20-119 attr, 120-139 unit, 140 val_w col, 141 val_b
__global__ void k_proj_tables(const float* __restrict__ dev_t, const float* __restrict__ pse_t,
                              const float* __restrict__ att_t, const float* __restrict__ unt_t,
                              const float* __restrict__ val_w, const float* __restrict__ val_b,
                              const float* __restrict__ W /*[384][128]*/,
                              float* __restrict__ out /*[142][384]*/) {
  __shared__ float src[128];
  int r = blockIdx.x;
  const float* s;
  if (r < 10)        s = dev_t + r * 128;
  else if (r < 20)   s = pse_t + (r - 10) * 128;
  else if (r < 120)  s = att_t + (r - 20) * 128;
  else if (r < 140)  s = unt_t + (r - 120) * 128;
  else if (r == 140) s = val_w;           // [128][1] contiguous
  else               s = val_b;
  int t = threadIdx.x;                    // 384 threads
  if (t < 128) src[t] = s[t];
  __syncthreads();
  const float* wr = W + t * 128;
  float acc = 0.f;
#pragma unroll 8
  for (int e = 0; e < 128; ++e) acc = fmaf(wr[e], src[e], acc);
  out[r * 384 + t] = acc;
}

// ---------------- P2: W2[768][128] = out_w @ out_proj_w (bf16), b2 = out_w@out_proj_b + out_b
__global__ void k_fuse_w2(const float* __restrict__ out_w /*[768][128]*/,
                          const float* __restrict__ opw /*[128][128]*/,
                          const float* __restrict__ opb /*[128]*/,
                          const float* __restrict__ out_b /*[768]*/,
                          unsigned short* __restrict__ W2 /*[768][128] bf16*/,
                          float* __restrict__ b2 /*[768]*/) {
  __shared__ float row[128];
  __shared__ float red[128];
  int r = blockIdx.x, c = threadIdx.x;    // 128 threads
  row[c] = out_w[r * 128 + c];
  __syncthreads();
  float acc = 0.f;
#pragma unroll 8
  for (int k = 0; k < 128; ++k) acc = fmaf(row[k], opw[k * 128 + c], acc);
  W2[r * 128 + c] = f32_bf16(acc);
  red[c] = row[c] * opb[c];
  __syncthreads();
#pragma unroll
  for (int s = 64; s > 0; s >>= 1) {
    if (c < s) red[c] += red[c + s];
    __syncthreads();
  }
  if (c == 0) b2[r] = red[0] + out_b[r];
}

// ---------------- main: 64 rows/block, 256 threads
// Phase A: thread = (row, head); fp32 attention -> meanO bf16 in LDS.
// Phase B: 4 waves; MFMA [64x128]@[128x768] with W2 from L2.

#define LDS_STRIDE 136   // bf16 elems/row: 272 B = 16B-aligned, 2-way bank alias (free)

__device__ __forceinline__ void load8f(float d[8], const float* __restrict__ p, int c) {
  float4 a = *(const float4*)(p + c);
  float4 b = *(const float4*)(p + c + 4);
  d[0] = a.x; d[1] = a.y; d[2] = a.z; d[3] = a.w;
  d[4] = b.x; d[5] = b.y; d[6] = b.z; d[7] = b.w;
}

__global__ __launch_bounds__(256, 2)
void k_main(const int* __restrict__ dev_ids, const int* __restrict__ pse_ids,
            const int* __restrict__ att_ids, const int* __restrict__ unt_ids,
            const float* __restrict__ values, const int* __restrict__ mask,
            const float* __restrict__ proj /*[142][384]*/,
            const float* __restrict__ bias /*in_proj_b[384]*/,
            const unsigned short* __restrict__ W2 /*[768][128] bf16*/,
            const float* __restrict__ b2 /*[768]*/,
            float* __restrict__ out /*[N][768]*/) {
  __shared__ __align__(16) unsigned short sMean[64 * LDS_STRIDE];

  const int tid = threadIdx.x;
  const int lr = tid >> 2;        // local row 0..63
  const int h  = tid & 3;         // head 0..3
  const int n  = blockIdx.x * 64 + lr;

  // ---- Phase A: attention for (row n, head h) ----
  {
    const float* p[5];
    p[0] = proj + (size_t)dev_ids[n] * 384;
    p[1] = proj + (size_t)(10 + pse_ids[n]) * 384;
    p[2] = proj + (size_t)(20 + att_ids[n]) * 384;
    p[3] = proj + (size_t)140 * 384;          // val_w projected
    p[4] = proj + (size_t)(120 + unt_ids[n]) * 384;
    const float* pvb = proj + (size_t)141 * 384;  // val_b projected
    const float val = values[n];
    float m[5];
#pragma unroll
    for (int t = 0; t < 5; ++t) m[t] = (float)mask[n * 5 + t];

    float s[25];
#pragma unroll
    for (int i = 0; i < 25; ++i) s[i] = 0.f;

#pragma unroll
    for (int dc = 0; dc < 4; ++dc) {
      const int qc = h * 32 + dc * 8;
      const int kc = qc + 128;
      float bq[8], bk[8];
      load8f(bq, bias, qc);
      load8f(bk, bias, kc);
      float qv[5][8], kv[5][8];
#pragma unroll
      for (int t = 0; t < 5; ++t) {
        float rq[8], rk[8];
        if (t == 3) {
          float aq[8], ab[8];
          load8f(aq, p[3], qc); load8f(ab, pvb, qc);
#pragma unroll
          for (int j = 0; j < 8; ++j) rq[j] = fmaf(val, aq[j], ab[j]);
          load8f(aq, p[3], kc); load8f(ab, pvb, kc);
#pragma unroll
          for (int j = 0; j < 8; ++j) rk[j] = fmaf(val, aq[j], ab[j]);
        } else {
          load8f(rq, p[t], qc);
          load8f(rk, p[t], kc);
        }
#pragma unroll
        for (int j = 0; j < 8; ++j) {
          qv[t][j] = fmaf(m[t], rq[j], bq[j]);
          kv[t][j] = fmaf(m[t], rk[j], bk[j]);
        }
      }
#pragma unroll
      for (int qt = 0; qt < 5; ++qt)
#pragma unroll
        for (int kt = 0; kt < 5; ++kt) {
          float acc = s[qt * 5 + kt];
#pragma unroll
          for (int j = 0; j < 8; ++j) acc = fmaf(qv[qt][j], kv[kt][j], acc);
          s[qt * 5 + kt] = acc;
        }
    }

    // softmax over kt (scaled), fold mean over qt into 5 value weights
    const float scale = 0.17677669529663687f;  // 1/sqrt(32)
    float w5[5] = {0.f, 0.f, 0.f, 0.f, 0.f};
#pragma unroll
    for (int qt = 0; qt < 5; ++qt) {
      const float* r = s + qt * 5;
      float mx = fmaxf(fmaxf(fmaxf(r[0], r[1]), fmaxf(r[2], r[3])), r[4]);
      float e[5], l = 0.f;
#pragma unroll
      for (int kt = 0; kt < 5; ++kt) { e[kt] = __expf((r[kt] - mx) * scale); l += e[kt]; }
      const float inv = 0.2f / l;
#pragma unroll
      for (int kt = 0; kt < 5; ++kt) w5[kt] = fmaf(e[kt], inv, w5[kt]);
    }
    const float sumw = w5[0] + w5[1] + w5[2] + w5[3] + w5[4];  // == 1 up to fp

    // mean_o = sum_k w5[k] * v[k]  (v[k] = m*proj + bias), bf16 into LDS
#pragma unroll
    for (int dc = 0; dc < 4; ++dc) {
      const int vc = 256 + h * 32 + dc * 8;
      float bv[8];
      load8f(bv, bias, vc);
      float acc[8];
#pragma unroll
      for (int j = 0; j < 8; ++j) acc[j] = sumw * bv[j];
#pragma unroll
      for (int kt = 0; kt < 5; ++kt) {
        float rv[8];
        if (kt == 3) {
          float av[8], ab[8];
          load8f(av, p[3], vc); load8f(ab, pvb, vc);
#pragma unroll
          for (int j = 0; j < 8; ++j) rv[j] = fmaf(val, av[j], ab[j]);
        } else {
          load8f(rv, p[kt], vc);
        }
        const float cw = w5[kt] * m[kt];
#pragma unroll
        for (int j = 0; j < 8; ++j) acc[j] = fmaf(cw, rv[j], acc[j]);
      }
      uint4 pk;
      pk.x = (unsigned)f32_bf16(acc[0]) | ((unsigned)f32_bf16(acc[1]) << 16);
      pk.y = (unsigned)f32_bf16(acc[2]) | ((unsigned)f32_bf16(acc[3]) << 16);
      pk.z = (unsigned)f32_bf16(acc[4]) | ((unsigned)f32_bf16(acc[5]) << 16);
      pk.w = (unsigned)f32_bf16(acc[6]) | ((unsigned)f32_bf16(acc[7]) << 16);
      *(uint4*)((char*)sMean + (size_t)lr * (LDS_STRIDE * 2) + h * 64 + dc * 16) = pk;
    }
  }
  __syncthreads();

  // ---- Phase B: out[64 rows][768] = meanO @ W2^T + b2 via MFMA 16x16x32 bf16 ----
  {
    const int w    = tid >> 6;   // wave 0..3 -> cols [w*192, w*192+192)
    const int lane = tid & 63;
    const int ln16 = lane & 15;  // A row within m-tile / B col within n-tile
    const int lq   = lane >> 4;  // quad 0..3

    // A fragments: 4 m-tiles x 4 k-steps, reused across 12 n-tiles
    bf16x8 afrag[4][4];
#pragma unroll
    for (int mt = 0; mt < 4; ++mt)
#pragma unroll
      for (int ks = 0; ks < 4; ++ks)
        afrag[mt][ks] = *(const bf16x8*)((const char*)sMean +
                          (size_t)(mt * 16 + ln16) * (LDS_STRIDE * 2) + ks * 64 + lq * 16);

    const int rowbase = blockIdx.x * 64;
#pragma unroll 2
    for (int nt = 0; nt < 12; ++nt) {
      const int col = w * 192 + nt * 16 + ln16;
      const unsigned short* bp = W2 + (size_t)col * 128 + lq * 8;
      bf16x8 bfrag[4];
#pragma unroll
      for (int ks = 0; ks < 4; ++ks)
        bfrag[ks] = *(const bf16x8*)(bp + ks * 32);

      floatx4 acc[4];
#pragma unroll
      for (int mt = 0; mt < 4; ++mt) acc[mt] = (floatx4){0.f, 0.f, 0.f, 0.f};
#pragma unroll
      for (int ks = 0; ks < 4; ++ks)
#pragma unroll
        for (int mt = 0; mt < 4; ++mt)
          acc[mt] = __builtin_amdgcn_mfma_f32_16x16x32_bf16(afrag[mt][ks], bfrag[ks], acc[mt], 0, 0, 0);

      const float bb = b2[col];
#pragma unroll
      for (int mt = 0; mt < 4; ++mt) {
        const int r0 = rowbase + mt * 16 + lq * 4;   // D: row=(lane>>4)*4+reg, col=lane&15
#pragma unroll
        for (int r = 0; r < 4; ++r)
          out[(size_t)(r0 + r) * 768 + col] = acc[mt][r] + bb;
      }
    }
  }
}

extern "C" void kernel_launch(void* const* d_in, const int* in_sizes, int n_in,
                              void* d_out, int out_size, void* d_ws, size_t ws_size,
                              hipStream_t stream) {
  const int*   dev_ids = (const int*)d_in[0];
  const int*   pse_ids = (const int*)d_in[1];
  const int*   att_ids = (const int*)d_in[2];
  const int*   unt_ids = (const int*)d_in[3];
  const float* values  = (const float*)d_in[4];
  const int*   mask    = (const int*)d_in[5];
  const float* dev_t   = (const float*)d_in[6];
  const float* pse_t   = (const float*)d_in[7];
  const float* att_t   = (const float*)d_in[8];
  const float* unt_t   = (const float*)d_in[9];
  const float* val_w   = (const float*)d_in[10];
  const float* val_b   = (const float*)d_in[11];
  const float* ipw     = (const float*)d_in[12];
  const float* ipb     = (const float*)d_in[13];
  const float* opw     = (const float*)d_in[14];
  const float* opb     = (const float*)d_in[15];
  const float* out_w   = (const float*)d_in[16];
  const float* out_b   = (const float*)d_in[17];
  float* out = (float*)d_out;

  const int N = in_sizes[0];

  // workspace layout (floats): proj[142*384]=54528 | b2[768] | W2 bf16 (16B-aligned)
  float* proj = (float*)d_ws;
  float* b2   = proj + 142 * 384;
  unsigned short* W2 = (unsigned short*)(b2 + 768);  // byte off 221184, 16B aligned
  // total ws use: 221184 + 196608 = 417792 B

  k_proj_tables<<<142, 384, 0, stream>>>(dev_t, pse_t, att_t, unt_t, val_w, val_b, ipw, proj);
  k_fuse_w2<<<768, 128, 0, stream>>>(out_w, opw, opb, out_b, W2, b2);
  k_main<<<N / 64, 256, 0, stream>>>(dev_ids, pse_ids, att_ids, unt_ids, values, mask,
                                     proj, ipb, W2, b2, out);
  (void)out_size; (void)ws_size; (void)n_in;
}

// Round 2
// 490.142 us; speedup vs baseline: 1.2103x; 1.2103x over previous
//
#include <hip/hip_runtime.h>

// CompositionalEmbedding on MI355X — round 2.
// Restructure: precompute the score bilinear form.
//   s[q,k] = m_q*m_k*(Pq_q . Pk_k) + m_q*(Pq_q . bk) + m_k*(bq . Pk_k) + bq . bk
// Token 3 (value proj) is linear in val -> expand over rows 140 (val_w) / 141 (val_b).
// Tables: D[142][142][4 heads], E[142][4], F[142][4], G[4]; V side as bf16
// PvB[143][dc=4][h=4][8] (row 142 = v-slice of in_proj_b) for coalesced 4-head loads.
// Phase B: out = meanO @ (out_w@out_proj_w)^T + fused bias, bf16 MFMA 16x16x32.

typedef __attribute__((ext_vector_type(8))) short bf16x8;
typedef __attribute__((ext_vector_type(4))) float floatx4;

__device__ __forceinline__ unsigned short f32_bf16(float f) {
  unsigned int x = __float_as_uint(f);
  x += 0x7FFFu + ((x >> 16) & 1u);   // RNE
  return (unsigned short)(x >> 16);
}

// ---------------- P1: proj[142][384] = {table rows, val_w, val_b} @ in_proj_w^T
__global__ void k_proj_tables(const float* __restrict__ dev_t, const float* __restrict__ pse_t,
                              const float* __restrict__ att_t, const float* __restrict__ unt_t,
                              const float* __restrict__ val_w, const float* __restrict__ val_b,
                              const float* __restrict__ W /*[384][128]*/,
                              float* __restrict__ out /*[142][384]*/) {
  __shared__ float src[128];
  int r = blockIdx.x;
  const float* s;
  if (r < 10)        s = dev_t + r * 128;
  else if (r < 20)   s = pse_t + (r - 10) * 128;
  else if (r < 120)  s = att_t + (r - 20) * 128;
  else if (r < 140)  s = unt_t + (r - 120) * 128;
  else if (r == 140) s = val_w;           // [128][1] contiguous
  else               s = val_b;
  int t = threadIdx.x;                    // 384 threads
  if (t < 128) src[t] = s[t];
  __syncthreads();
  const float* wr = W + t * 128;
  float acc = 0.f;
#pragma unroll 8
  for (int e = 0; e < 128; ++e) acc = fmaf(wr[e], src[e], acc);
  out[r * 384 + t] = acc;
}

// ---------------- P2: W2[768][128] bf16 = out_w @ out_proj_w ; b2 = out_w@out_proj_b + out_b
__global__ void k_fuse_w2(const float* __restrict__ out_w /*[768][128]*/,
                          const float* __restrict__ opw /*[128][128]*/,
                          const float* __restrict__ opb /*[128]*/,
                          const float* __restrict__ out_b /*[768]*/,
                          unsigned short* __restrict__ W2 /*[768][128] bf16*/,
                          float* __restrict__ b2 /*[768]*/) {
  __shared__ float row[128];
  __shared__ float red[128];
  int r = blockIdx.x, c = threadIdx.x;    // 128 threads
  row[c] = out_w[r * 128 + c];
  __syncthreads();
  float acc = 0.f;
#pragma unroll 8
  for (int k = 0; k < 128; ++k) acc = fmaf(row[k], opw[k * 128 + c], acc);
  W2[r * 128 + c] = f32_bf16(acc);
  red[c] = row[c] * opb[c];
  __syncthreads();
#pragma unroll
  for (int s = 64; s > 0; s >>= 1) {
    if (c < s) red[c] += red[c + s];
    __syncthreads();
  }
  if (c == 0) b2[r] = red[0] + out_b[r];
}

// ---------------- P3: score dot tables + bf16 V table
// D[q][k][h] = (q-slice of proj[q], head h) . (k-slice of proj[k], head h)
// E[q][h] = Pq_q . bk ; F[k][h] = bq . Pk_k ; G[h] = bq . bk
// PvB[row][dc][h][8] bf16; row 142 = v-slice of bias.
__global__ void k_dots(const float* __restrict__ proj, const float* __restrict__ bias,
                       float* __restrict__ D, float* __restrict__ E,
                       float* __restrict__ F, float* __restrict__ G,
                       unsigned short* __restrict__ PvB) {
  __shared__ float qs[128];
  const int q = blockIdx.x;     // 0..141
  const int t = threadIdx.x;    // 256
  if (t < 128) qs[t] = proj[q * 384 + t];
  __syncthreads();
  for (int o = t; o < 568; o += 256) {
    const int k = o >> 2, h = o & 3;
    const float* kp = proj + k * 384 + 128 + h * 32;
    const float* qp = qs + h * 32;
    float acc = 0.f;
#pragma unroll
    for (int d = 0; d < 32; ++d) acc = fmaf(qp[d], kp[d], acc);
    D[(size_t)(q * 142 + k) * 4 + h] = acc;
  }
  if (t < 4) {
    const int h = t;
    float e = 0.f, f = 0.f;
#pragma unroll
    for (int d = 0; d < 32; ++d) {
      e = fmaf(qs[h * 32 + d], bias[128 + h * 32 + d], e);
      f = fmaf(bias[h * 32 + d], proj[q * 384 + 128 + h * 32 + d], f);
    }
    E[q * 4 + h] = e;
    F[q * 4 + h] = f;
    if (q == 0) {
      float g = 0.f;
#pragma unroll
      for (int d = 0; d < 32; ++d) g = fmaf(bias[h * 32 + d], bias[128 + h * 32 + d], g);
      G[h] = g;
    }
  }
  if (t >= 128) {
    const int x = t - 128;                       // 0..127, col in v-slice
    const int h = x >> 5, dc = (x >> 3) & 3, j = x & 7;
    PvB[q * 128 + dc * 32 + h * 8 + j] = f32_bf16(proj[q * 384 + 256 + x]);
    if (q == 0) PvB[142 * 128 + dc * 32 + h * 8 + j] = f32_bf16(bias[256 + x]);
  }
}

// ---------------- main: 64 rows/block, 256 threads
#define LDS_STRIDE 136   // bf16 elems/row: 272 B, 16B-aligned, 2-way bank alias (free)

__device__ __forceinline__ void unpack8(float d[8], uint4 p) {
  d[0] = __uint_as_float(p.x << 16); d[1] = __uint_as_float(p.x & 0xffff0000u);
  d[2] = __uint_as_float(p.y << 16); d[3] = __uint_as_float(p.y & 0xffff0000u);
  d[4] = __uint_as_float(p.z << 16); d[5] = __uint_as_float(p.z & 0xffff0000u);
  d[6] = __uint_as_float(p.w << 16); d[7] = __uint_as_float(p.w & 0xffff0000u);
}

__global__ __launch_bounds__(256, 2)
void k_main(const int* __restrict__ dev_ids, const int* __restrict__ pse_ids,
            const int* __restrict__ att_ids, const int* __restrict__ unt_ids,
            const float* __restrict__ values, const int* __restrict__ mask,
            const float* __restrict__ D, const float* __restrict__ E,
            const float* __restrict__ F, const float* __restrict__ G,
            const unsigned short* __restrict__ PvB,
            const unsigned short* __restrict__ W2 /*[768][128] bf16*/,
            const float* __restrict__ b2 /*[768]*/,
            float* __restrict__ out /*[N][768]*/) {
  __shared__ __align__(16) unsigned short sMean[64 * LDS_STRIDE];

  const int tid = threadIdx.x;
  const int lr = tid >> 2;        // local row 0..63
  const int h  = tid & 3;         // head 0..3 (adjacent lanes = 4 heads -> coalesced D gathers)
  const int n  = blockIdx.x * 64 + lr;

  // ---- Phase A: scores from precomputed dots, then weighted V combine ----
  {
    int R[4];
    R[0] = dev_ids[n];
    R[1] = 10 + pse_ids[n];
    R[2] = 20 + att_ids[n];
    R[3] = 120 + unt_ids[n];     // token 4
    const float val = values[n];
    float m[5];
#pragma unroll
    for (int t = 0; t < 5; ++t) m[t] = (float)mask[n * 5 + t];
    const float mi[4] = {m[0], m[1], m[2], m[4]};

    // gathers (lane h gives 16B coalescing across the 4 head-lanes)
    float Dqk[4][4], Dw_k[4], Db_k[4], Dq_w[4], Dq_b[4], Eq[4], Fk[4];
#pragma unroll
    for (int i = 0; i < 4; ++i) {
#pragma unroll
      for (int j = 0; j < 4; ++j)
        Dqk[i][j] = D[(size_t)(R[i] * 142 + R[j]) * 4 + h];
      Dw_k[i] = D[(size_t)(140 * 142 + R[i]) * 4 + h];
      Db_k[i] = D[(size_t)(141 * 142 + R[i]) * 4 + h];
      Dq_w[i] = D[(size_t)(R[i] * 142 + 140) * 4 + h];
      Dq_b[i] = D[(size_t)(R[i] * 142 + 141) * 4 + h];
      Eq[i]   = E[R[i] * 4 + h];
      Fk[i]   = F[R[i] * 4 + h];
    }
    // wave-uniform-per-head constants
    const float Dww = D[(size_t)(140 * 142 + 140) * 4 + h];
    const float Dwb = D[(size_t)(140 * 142 + 141) * 4 + h];
    const float Dbw = D[(size_t)(141 * 142 + 140) * 4 + h];
    const float Dbb = D[(size_t)(141 * 142 + 141) * 4 + h];
    const float Ew = E[140 * 4 + h], Eb = E[141 * 4 + h];
    const float Fw = F[140 * 4 + h], Fb = F[141 * 4 + h];
    const float Gh = G[h];

    const float E3  = val * Ew + Eb;                                  // Pq3 . bk
    const float F3  = val * Fw + Fb;                                  // bq . Pk3
    const float D33 = val * val * Dww + val * (Dwb + Dbw) + Dbb;

    const int ti[4] = {0, 1, 2, 4};
    float s[25];
#pragma unroll
    for (int i = 0; i < 4; ++i)
#pragma unroll
      for (int j = 0; j < 4; ++j)
        s[ti[i] * 5 + ti[j]] = mi[i] * (mi[j] * Dqk[i][j] + Eq[i]) + mi[j] * Fk[j] + Gh;
#pragma unroll
    for (int j = 0; j < 4; ++j)
      s[3 * 5 + ti[j]] = m[3] * (mi[j] * (val * Dw_k[j] + Db_k[j]) + E3) + mi[j] * Fk[j] + Gh;
#pragma unroll
    for (int i = 0; i < 4; ++i)
      s[ti[i] * 5 + 3] = mi[i] * (m[3] * (val * Dq_w[i] + Dq_b[i]) + Eq[i]) + m[3] * F3 + Gh;
    s[3 * 5 + 3] = m[3] * (m[3] * D33 + E3) + m[3] * F3 + Gh;

    // softmax over k per q-row (scaled), mean over q folded into w5
    const float scale = 0.17677669529663687f;  // 1/sqrt(32)
    float w5[5] = {0.f, 0.f, 0.f, 0.f, 0.f};
#pragma unroll
    for (int qt = 0; qt < 5; ++qt) {
      const float* r = s + qt * 5;
      float mx = fmaxf(fmaxf(fmaxf(r[0], r[1]), fmaxf(r[2], r[3])), r[4]);
      float e[5], l = 0.f;
#pragma unroll
      for (int kt = 0; kt < 5; ++kt) { e[kt] = __expf((r[kt] - mx) * scale); l += e[kt]; }
      const float inv = 0.2f / l;
#pragma unroll
      for (int kt = 0; kt < 5; ++kt) w5[kt] = fmaf(e[kt], inv, w5[kt]);
    }
    const float sumw = w5[0] + w5[1] + w5[2] + w5[3] + w5[4];

    // meanO = sum of 7 weighted rows of PvB (bf16), fp32 accumulate
    const int   vr[7] = {R[0], R[1], R[2], R[3], 140, 141, 142};
    const float vc[7] = {w5[0] * m[0], w5[1] * m[1], w5[2] * m[2], w5[4] * m[4],
                         w5[3] * m[3] * val, w5[3] * m[3], sumw};
#pragma unroll
    for (int dc = 0; dc < 4; ++dc) {
      float acc[8] = {0.f, 0.f, 0.f, 0.f, 0.f, 0.f, 0.f, 0.f};
#pragma unroll
      for (int p = 0; p < 7; ++p) {
        uint4 pk = *(const uint4*)(PvB + (size_t)vr[p] * 128 + dc * 32 + h * 8);
        float v[8];
        unpack8(v, pk);
#pragma unroll
        for (int j = 0; j < 8; ++j) acc[j] = fmaf(vc[p], v[j], acc[j]);
      }
      uint4 pk;
      pk.x = (unsigned)f32_bf16(acc[0]) | ((unsigned)f32_bf16(acc[1]) << 16);
      pk.y = (unsigned)f32_bf16(acc[2]) | ((unsigned)f32_bf16(acc[3]) << 16);
      pk.z = (unsigned)f32_bf16(acc[4]) | ((unsigned)f32_bf16(acc[5]) << 16);
      pk.w = (unsigned)f32_bf16(acc[6]) | ((unsigned)f32_bf16(acc[7]) << 16);
      *(uint4*)((char*)sMean + (size_t)lr * (LDS_STRIDE * 2) + h * 64 + dc * 16) = pk;
    }
  }
  __syncthreads();

  // ---- Phase B: out[64][768] = meanO @ W2^T + b2 via MFMA 16x16x32 bf16 ----
  {
    const int w    = tid >> 6;   // wave 0..3 -> cols [w*192, +192)
    const int lane = tid & 63;
    const int ln16 = lane & 15;
    const int lq   = lane >> 4;

    bf16x8 afrag[4][4];
#pragma unroll
    for (int mt = 0; mt < 4; ++mt)
#pragma unroll
      for (int ks = 0; ks < 4; ++ks)
        afrag[mt][ks] = *(const bf16x8*)((const char*)sMean +
                          (size_t)(mt * 16 + ln16) * (LDS_STRIDE * 2) + ks * 64 + lq * 16);

    const int rowbase = blockIdx.x * 64;
#pragma unroll 2
    for (int nt = 0; nt < 12; ++nt) {
      const int col = w * 192 + nt * 16 + ln16;
      const unsigned short* bp = W2 + (size_t)col * 128 + lq * 8;
      bf16x8 bfrag[4];
#pragma unroll
      for (int ks = 0; ks < 4; ++ks)
        bfrag[ks] = *(const bf16x8*)(bp + ks * 32);

      floatx4 acc[4];
#pragma unroll
      for (int mt = 0; mt < 4; ++mt) acc[mt] = (floatx4){0.f, 0.f, 0.f, 0.f};
#pragma unroll
      for (int ks = 0; ks < 4; ++ks)
#pragma unroll
        for (int mt = 0; mt < 4; ++mt)
          acc[mt] = __builtin_amdgcn_mfma_f32_16x16x32_bf16(afrag[mt][ks], bfrag[ks], acc[mt], 0, 0, 0);

      const float bb = b2[col];
#pragma unroll
      for (int mt = 0; mt < 4; ++mt) {
        const int r0 = rowbase + mt * 16 + lq * 4;   // D: row=(lane>>4)*4+reg, col=lane&15
#pragma unroll
        for (int r = 0; r < 4; ++r)
          out[(size_t)(r0 + r) * 768 + col] = acc[mt][r] + bb;
      }
    }
  }
}

extern "C" void kernel_launch(void* const* d_in, const int* in_sizes, int n_in,
                              void* d_out, int out_size, void* d_ws, size_t ws_size,
                              hipStream_t stream) {
  const int*   dev_ids = (const int*)d_in[0];
  const int*   pse_ids = (const int*)d_in[1];
  const int*   att_ids = (const int*)d_in[2];
  const int*   unt_ids = (const int*)d_in[3];
  const float* values  = (const float*)d_in[4];
  const int*   mask    = (const int*)d_in[5];
  const float* dev_t   = (const float*)d_in[6];
  const float* pse_t   = (const float*)d_in[7];
  const float* att_t   = (const float*)d_in[8];
  const float* unt_t   = (const float*)d_in[9];
  const float* val_w   = (const float*)d_in[10];
  const float* val_b   = (const float*)d_in[11];
  const float* ipw     = (const float*)d_in[12];
  const float* ipb     = (const float*)d_in[13];
  const float* opw     = (const float*)d_in[14];
  const float* opb     = (const float*)d_in[15];
  const float* out_w   = (const float*)d_in[16];
  const float* out_b   = (const float*)d_in[17];
  float* out = (float*)d_out;

  const int N = in_sizes[0];

  // workspace layout (float units):
  // proj 54528 | b2 768 | W2(bf16) 24576 | D 80656 | E 568 | F 568 | G 4 | PvB(bf16) 9152
  float* proj = (float*)d_ws;
  float* b2   = proj + 54528;
  unsigned short* W2 = (unsigned short*)(b2 + 768);
  float* D = (float*)(W2 + 768 * 128);
  float* E = D + 142 * 142 * 4;
  float* F = E + 142 * 4;
  float* G = F + 142 * 4;
  unsigned short* PvB = (unsigned short*)(G + 4);   // byte offset 646672, 16B aligned
  // total ws use ~683 KB

  k_proj_tables<<<142, 384, 0, stream>>>(dev_t, pse_t, att_t, unt_t, val_w, val_b, ipw, proj);
  k_fuse_w2<<<768, 128, 0, stream>>>(out_w, opw, opb, out_b, W2, b2);
  k_dots<<<142, 256, 0, stream>>>(proj, ipb, D, E, F, G, PvB);
  k_main<<<N / 64, 256, 0, stream>>>(dev_ids, pse_ids, att_ids, unt_ids, values, mask,
                                     D, E, F, G, PvB, W2, b2, out);
  (void)out_size; (void)ws_size; (void)n_in;
}